// Round 11
// baseline (172.338 us; speedup 1.0000x reference)
//
#include <hip/hip_runtime.h>

typedef unsigned short u16;
typedef __bf16 bf16;
typedef bf16 bf16x8 __attribute__((ext_vector_type(8)));
typedef float f32x4 __attribute__((ext_vector_type(4)));

#define SEQ     2048
#define BATCH   2
#define DM      1024
#define DI      1024
#define NROW    (BATCH*SEQ)      // 4096
#define NSTATE  16
#define NCHUNK  64
#define CLEN    32               // SEQ / NCHUNK

static_assert(SEQ == NCHUNK * CLEN, "chunking must cover SEQ");

__device__ __forceinline__ u16 f2bf(float f) {
  unsigned u = __builtin_bit_cast(unsigned, f);
  u += 0x7FFFu + ((u >> 16) & 1u);   // round-to-nearest-even
  return (u16)(u >> 16);
}
__device__ __forceinline__ float bf2f(u16 u) {
  return __builtin_bit_cast(float, (unsigned)u << 16);
}
__device__ __forceinline__ float sigm(float x) { return 1.f / (1.f + __expf(-x)); }

// ---------------- fused fp32 -> bf16 convert for all 4 tensors ----------------
__global__ __launch_bounds__(256) void k_cvt_all(
    const float* __restrict__ x, const float* __restrict__ Win,
    const float* __restrict__ Wdt, const float* __restrict__ Wout,
    u16* __restrict__ xbf, u16* __restrict__ winbf,
    u16* __restrict__ wdtbf, u16* __restrict__ woutbf)
{
  long i = (long)blockIdx.x * 256 + threadIdx.x;
  const float* src; u16* dst; long off;
  if (i < 1048576)            { src = x;    dst = xbf;    off = i; }
  else if (i < 1572864)       { src = Win;  dst = winbf;  off = i - 1048576; }
  else if (i < 1835008)       { src = Wdt;  dst = wdtbf;  off = i - 1572864; }
  else                        { src = Wout; dst = woutbf; off = i - 1835008; }
  float4 v = reinterpret_cast<const float4*>(src)[off];
  ushort4 o;
  o.x = f2bf(v.x); o.y = f2bf(v.y); o.z = f2bf(v.z); o.w = f2bf(v.w);
  reinterpret_cast<ushort4*>(dst)[off] = o;
}

// ---------------- bf16 MFMA GEMM: C[M][N] = A[M][K] * B[N][K]^T ----------------
// 128x128 tile, BK=32, 16x16x32 frags 4x4/wave, 4-buffer counted-vmcnt deep
// pipeline (T4): tiles t+1,t+2 stay in flight across the per-iter barrier
// ("s_waitcnt vmcnt(8); s_barrier" -- never drains to 0). 4 buffers make the
// write-after-read distance 2 barriers (slot (t+2)%4 last read iter t-2).
// Both-sides granule swizzle: 64B row = 4x16B granules, granule ^= row&3.
// Governing model (R1-R10): staging-ingestion ceiling ~6.4 TB/s aggregate;
// 128^2 tiles minimize staged bytes (G2/G3: 134 MB); pipeline depth replaces
// block residency at 1 blk/CU.
// EPI 0: fp32 store. EPI 1: bf16 x_proj / bf16 silu(res).
// EPI 3: bf16 softplus(delta) + fused scanA (4 chunks x 128 d per block).

__device__ __forceinline__ void gload16(const u16* g, u16* l) {
  __builtin_amdgcn_global_load_lds((const __attribute__((address_space(1))) void*)g,
                                   (__attribute__((address_space(3))) void*)l,
                                   16, 0, 0);
}

template<int EPI, int GX>
__global__ __launch_bounds__(256, 2) void k_gemm(
    const u16* __restrict__ A, const u16* __restrict__ B,
    float* __restrict__ outf, u16* __restrict__ outb, u16* __restrict__ outb2,
    const float* __restrict__ bias,
    const float* __restrict__ A_log, const float* __restrict__ Bp,
    float* __restrict__ hfin, float* __restrict__ sumdt,
    int M, int N, int K)
{
  // 4 bufs x (A 128x32 + B 128x32) bf16 = 64 KB total
  __shared__ __align__(16) u16 smem[32768];
  u16* sA = smem;                    // 4 x 4096 u16
  u16* sB = smem + 16384;            // 4 x 4096 u16
  const int t = threadIdx.x;
  const int wave = t >> 6, lane = t & 63;
  const int lr = lane & 15, kb = lane >> 4;          // frag row, k-quarter
  const int wr = wave >> 1, wc = wave & 1;

  // XCD-aware bijective swizzle (nwg % 8 == 0)
  const int nwg = gridDim.x, bid = blockIdx.x;
  const int wg  = (bid & 7) * (nwg >> 3) + (bid >> 3);
  const long bm = (long)(wg / GX) * 128;
  const long bn = (long)(wg % GX) * 128;

  f32x4 acc[4][4] = {};

  // staging: per STAGE call 64 rows x 32 cols (4KB); thread t -> row t>>2,
  // LDS granule t&3, global granule (t&3)^(row&3) (pre-swizzled source).
  const int srow = t >> 2;                            // 0..63
  const int gslot8 = (((t & 3) ^ (srow & 3)) * 8);
  const u16* gA0 = A + (bm + srow) * (long)K + gslot8;
  const u16* gB0 = B + (bn + srow) * (long)K + gslot8;

  auto STAGE = [&](int buf, int k0) {
    gload16(gA0 + k0,            &sA[buf * 4096 + wave * 512]);
    gload16(gA0 + 64 * (long)K + k0, &sA[buf * 4096 + 2048 + wave * 512]);
    gload16(gB0 + k0,            &sB[buf * 4096 + wave * 512]);
    gload16(gB0 + 64 * (long)K + k0, &sB[buf * 4096 + 2048 + wave * 512]);
  };

  const int xr = lr & 3;           // read-side XOR (granule units)
  const int NT = K / 32;
  STAGE(0, 0);
  STAGE(1, 32);
  for (int tt = 0; tt < NT; ++tt) {
    STAGE((tt + 2) & 3, (tt + 2 < NT) ? (tt + 2) * 32 : 0);  // dummy at tail
    // tile tt ready (tiles tt+1, tt+2 = 8 loads stay in flight)
    asm volatile("s_waitcnt vmcnt(8)\n\ts_barrier" ::: "memory");
    const int cur = tt & 3;
    const u16* pa = &sA[cur * 4096];
    const u16* pb = &sB[cur * 4096];
    const int co = (kb ^ xr) * 8;
    bf16x8 af[4], bfr[4];
    #pragma unroll
    for (int mi = 0; mi < 4; ++mi)
      af[mi] = *reinterpret_cast<const bf16x8*>(pa + (wr * 64 + mi * 16 + lr) * 32 + co);
    #pragma unroll
    for (int ni = 0; ni < 4; ++ni)
      bfr[ni] = *reinterpret_cast<const bf16x8*>(pb + (wc * 64 + ni * 16 + lr) * 32 + co);
    #pragma unroll
    for (int mi = 0; mi < 4; ++mi)
      #pragma unroll
      for (int ni = 0; ni < 4; ++ni)
        acc[mi][ni] = __builtin_amdgcn_mfma_f32_16x16x32_bf16(
            af[mi], bfr[ni], acc[mi][ni], 0, 0, 0);
  }
  // all buffers dead after loop; one barrier before LDS reuse in EPI3
  __syncthreads();

  // ---------------- epilogue ----------------
  float* sDelta = (float*)smem;    // EPI3: 128x128 fp32 = 64KB (post-loop reuse)

  #pragma unroll
  for (int mi = 0; mi < 4; ++mi) {
    const long row0 = bm + wr * 64 + mi * 16 + kb * 4;   // C/D row=(lane>>4)*4+j
    #pragma unroll
    for (int ni = 0; ni < 4; ++ni) {
      const long col = bn + wc * 64 + ni * 16 + lr;      // C/D col=lane&15
      #pragma unroll
      for (int j = 0; j < 4; ++j) {
        const float v = acc[mi][ni][j];
        const long r = row0 + j;
        if (EPI == 0) {
          outf[r * N + col] = v;
        } else if (EPI == 1) {
          if (bn < DI) outb[r * DI + col] = f2bf(v);                    // x_proj
          else         outb2[r * DI + (col - DI)] = f2bf(v * sigm(v));  // silu(res)
        } else if (EPI == 3) {
          float z = v + bias[col];
          float sp = fmaxf(z, 0.f) + log1pf(__expf(-fabsf(z)));
          outb[r * N + col] = f2bf(sp);                  // delta bf16 for scanB
          sDelta[(int)(r - bm) * 128 + (int)(col - bn)] = sp;
        }
      }
    }
  }

  if (EPI == 3) {
    // fused scanA: block covers 4 chunks x 128 d; thread -> d x 2 chunks
    __syncthreads();
    const int dl = t & 127;
    const int d  = (int)bn + dl;
    const int b  = (int)(bm >> 11);
    const int c0 = (int)((bm & 2047) >> 5);
    float Aa[NSTATE], Bb[NSTATE];
    #pragma unroll
    for (int n = 0; n < NSTATE; ++n) {
      Aa[n] = -__expf(A_log[d * NSTATE + n]);
      Bb[n] = Bp[d * NSTATE + n];
    }
    for (int cl = (t >> 7) * 2; cl < (t >> 7) * 2 + 2; ++cl) {
      float h[NSTATE];
      #pragma unroll
      for (int n = 0; n < NSTATE; ++n) h[n] = 0.f;
      float sdt = 0.f;
      const long grow0 = bm + cl * 32;
      for (int i = 0; i < CLEN; ++i) {
        float dt = sDelta[(cl * 32 + i) * 128 + dl];
        float xv = bf2f(A[(grow0 + i) * (long)K + d]);   // A == xc_bf
        sdt += dt;
        float dx = dt * xv;
        #pragma unroll
        for (int n = 0; n < NSTATE; ++n) {
          float da = __expf(dt * Aa[n]);
          h[n] = fmaf(da, h[n], dx * Bb[n]);
        }
      }
      const int cg = c0 + cl;
      const long hb = ((long)(b * NCHUNK + cg) * NSTATE) * DI + d;
      #pragma unroll
      for (int n = 0; n < NSTATE; ++n) hfin[hb + (long)n * DI] = h[n];
      sumdt[(long)(b * NCHUNK + cg) * DI + d] = sdt;
    }
  }
}

// ---------------- causal depthwise conv (K=4) + silu -> bf16, x8 vectorized ----
__global__ __launch_bounds__(256) void k_conv(
    const u16* __restrict__ xproj, const float* __restrict__ convw,
    const float* __restrict__ convb, u16* __restrict__ xcbf)
{
  const int idx = blockIdx.x * 256 + threadIdx.x;   // (m, d-octet)
  const int d0 = (idx & 127) * 8;
  const int m  = idx >> 7;
  const int l  = m & (SEQ - 1);
  float acc[8];
  #pragma unroll
  for (int di = 0; di < 8; ++di) acc[di] = convb[d0 + di];
  #pragma unroll
  for (int k = 0; k < 4; ++k) {
    if (l + k - 3 >= 0) {
      ushort4 v2 = *reinterpret_cast<const ushort4*>(&xproj[(long)(m + k - 3) * DI + d0]);
      ushort4 v3 = *reinterpret_cast<const ushort4*>(&xproj[(long)(m + k - 3) * DI + d0 + 4]);
      const u16 vv[8] = {v2.x, v2.y, v2.z, v2.w, v3.x, v3.y, v3.z, v3.w};
      #pragma unroll
      for (int di = 0; di < 8; ++di)
        acc[di] = fmaf(convw[(d0 + di) * 4 + k], bf2f(vv[di]), acc[di]);
    }
  }
  u16 ov[8];
  #pragma unroll
  for (int di = 0; di < 8; ++di) {
    float s = acc[di] * sigm(acc[di]);
    ov[di] = f2bf(s);
  }
  ushort4 o0 = {ov[0], ov[1], ov[2], ov[3]}, o1 = {ov[4], ov[5], ov[6], ov[7]};
  *reinterpret_cast<ushort4*>(&xcbf[(long)m * DI + d0]) = o0;
  *reinterpret_cast<ushort4*>(&xcbf[(long)m * DI + d0 + 4]) = o1;
}

// ---------------- scan combine + pass B ----------------
__global__ __launch_bounds__(256) void k_combine(
    const float* __restrict__ hfin, const float* __restrict__ sumdt_buf,
    const float* __restrict__ A_log, float* __restrict__ hstart)
{
  const int idx = blockIdx.x * 256 + threadIdx.x;   // 32768 threads
  const int d = idx & (DI - 1);
  const int n = (idx >> 10) & (NSTATE - 1);
  const int b = idx >> 14;
  const float Aa = -__expf(A_log[d * NSTATE + n]);
  float h = 0.f;
  for (int c = 0; c < NCHUNK; ++c) {
    const long sb = ((long)(b * NCHUNK + c) * NSTATE + n) * DI + d;
    hstart[sb] = h;
    float sdt = sumdt_buf[(long)(b * NCHUNK + c) * DI + d];
    h = fmaf(__expf(Aa * sdt), h, hfin[sb]);
  }
}

__global__ __launch_bounds__(256) void k_scanB(
    const u16* __restrict__ delta, const u16* __restrict__ xc,
    const float* __restrict__ A_log, const float* __restrict__ Bp,
    const float* __restrict__ Cp, const float* __restrict__ Dp,
    const u16* __restrict__ sres, const float* __restrict__ hstart,
    u16* __restrict__ gated)
{
  const int tid = threadIdx.x, blk = blockIdx.x;    // 512 blocks
  const int d = (blk & 3) * 256 + tid;
  const int c = (blk >> 2) & (NCHUNK - 1);
  const int b = blk >> 8;
  float Aa[NSTATE], Bb[NSTATE], Cc[NSTATE], h[NSTATE];
  #pragma unroll
  for (int n = 0; n < NSTATE; ++n) {
    Aa[n] = -__expf(A_log[d * NSTATE + n]);
    Bb[n] = Bp[d * NSTATE + n];
    Cc[n] = Cp[d * NSTATE + n];
  }
  const float Dd = Dp[d];
  const long sb = ((long)(b * NCHUNK + c) * NSTATE) * DI + d;
  #pragma unroll
  for (int n = 0; n < NSTATE; ++n) h[n] = hstart[sb + (long)n * DI];
  const long base = ((long)(b * SEQ + c * CLEN)) * DI + d;
  for (int i = 0; i < CLEN; ++i) {
    float dt = bf2f(delta[base + (long)i * DI]);
    float x  = bf2f(xc[base + (long)i * DI]);
    float dx = dt * x;
    float y = 0.f;
    #pragma unroll
    for (int n = 0; n < NSTATE; ++n) {
      float da = __expf(dt * Aa[n]);
      h[n] = fmaf(da, h[n], dx * Bb[n]);
      y = fmaf(h[n], Cc[n], y);
    }
    float xs = fmaf(x, Dd, y);
    float g = xs * bf2f(sres[base + (long)i * DI]);
    gated[base + (long)i * DI] = f2bf(g);
  }
}

// ---------------- host launch ----------------
extern "C" void kernel_launch(void* const* d_in, const int* in_sizes, int n_in,
                              void* d_out, int out_size, void* d_ws, size_t ws_size,
                              hipStream_t stream)
{
  const float* x      = (const float*)d_in[0];
  const float* W_in   = (const float*)d_in[1];
  const float* conv_w = (const float*)d_in[2];
  const float* conv_b = (const float*)d_in[3];
  const float* W_dt   = (const float*)d_in[4];
  const float* b_dt   = (const float*)d_in[5];
  const float* A_log  = (const float*)d_in[6];
  const float* Bp     = (const float*)d_in[7];
  const float* Cp     = (const float*)d_in[8];
  const float* Dp     = (const float*)d_in[9];
  const float* W_out  = (const float*)d_in[10];
  float* out = (float*)d_out;

  const long MD = (long)NROW * DI;          // 4194304

  char* ws = (char*)d_ws;
  u16*   xproj_bf = (u16*)ws;               ws += MD * 2;   // x_proj bf16
  u16*   silu_bf  = (u16*)ws;               ws += MD * 2;   // silu(res) bf16
  u16*   delta_bf = (u16*)ws;               ws += MD * 2;   // softplus out bf16
  u16*   xc_bf    = (u16*)ws;               ws += MD * 2;   // conv+silu bf16
  u16*   xbf      = (u16*)ws;               ws += MD * 2;   // x bf16; later gated
  u16*   Win_bf   = (u16*)ws;               ws += (long)2 * DI * DM * 2;
  u16*   Wdt_bf   = (u16*)ws;               ws += (long)DI * DI * 2;
  u16*   Wout_bf  = (u16*)ws;               ws += (long)DM * DI * 2;
  float* hfin     = (float*)ws;             ws += (long)BATCH * NCHUNK * NSTATE * DI * 4;
  float* sumdt    = (float*)ws;             ws += (long)BATCH * NCHUNK * DI * 4;
  float* hstart   = (float*)ws;             ws += (long)BATCH * NCHUNK * NSTATE * DI * 4;

  u16* gated = xbf;      // alias: x_bf16 dead before gated is written

  // 1) fused fp32 -> bf16 conversion (x, W_in, W_dt, W_out)
  k_cvt_all<<<dim3(8192), dim3(256), 0, stream>>>(
      x, W_in, W_dt, W_out, xbf, Win_bf, Wdt_bf, Wout_bf);

  // 2) GEMM1: xr = x @ W_in^T -> x_proj (bf16), silu_res (bf16)
  //    128x128 tile, grid 32x16 = 512 blocks (2/CU), staged 256 MB
  k_gemm<1, 16><<<dim3(512), dim3(256), 0, stream>>>(
      xbf, Win_bf, nullptr, xproj_bf, silu_bf, nullptr,
      nullptr, nullptr, nullptr, nullptr, NROW, 2 * DI, DM);

  // 3) causal depthwise conv + silu -> bf16 (x8 vectorized)
  k_conv<<<dim3((unsigned)(MD / 8 / 256)), dim3(256), 0, stream>>>(
      xproj_bf, conv_w, conv_b, xc_bf);

  // 4) GEMM2 + fused scanA: delta = softplus(xc @ W_dt^T + b_dt); local scan
  //    128x128 tile, grid 32x8 = 256 blocks (1/CU), staged 134 MB
  k_gemm<3, 8><<<dim3(256), dim3(256), 0, stream>>>(
      xc_bf, Wdt_bf, nullptr, delta_bf, nullptr, b_dt,
      A_log, Bp, hfin, sumdt, NROW, DI, DI);

  // 5) combine + scanB
  k_combine<<<dim3(BATCH * NSTATE * DI / 256), dim3(256), 0, stream>>>(
      hfin, sumdt, A_log, hstart);
  k_scanB<<<dim3(BATCH * NCHUNK * (DI / 256)), dim3(256), 0, stream>>>(
      delta_bf, xc_bf, A_log, Bp, Cp, Dp, silu_bf, hstart, gated);

  // 6) GEMM3: out = gated @ W_out^T (fp32 out)
  //    128x128 tile, grid 32x8 = 256 blocks (1/CU), staged 134 MB
  k_gemm<0, 8><<<dim3(256), dim3(256), 0, stream>>>(
      gated, Wout_bf, out, nullptr, nullptr, nullptr,
      nullptr, nullptr, nullptr, nullptr, NROW, DM, DI);
}

// Round 12
// 160.578 us; speedup vs baseline: 1.0732x; 1.0732x over previous
//
#include <hip/hip_runtime.h>

typedef unsigned short u16;
typedef __bf16 bf16;
typedef bf16 bf16x8 __attribute__((ext_vector_type(8)));
typedef float f32x16 __attribute__((ext_vector_type(16)));

#define SEQ     2048
#define BATCH   2
#define DM      1024
#define DI      1024
#define NROW    (BATCH*SEQ)      // 4096
#define NSTATE  16
#define NCHUNK  64
#define CLEN    32               // SEQ / NCHUNK
#define BK      64               // K-step (u16 elems); granule-swizzled LDS

static_assert(SEQ == NCHUNK * CLEN, "chunking must cover SEQ");

__device__ __forceinline__ u16 f2bf(float f) {
  unsigned u = __builtin_bit_cast(unsigned, f);
  u += 0x7FFFu + ((u >> 16) & 1u);   // round-to-nearest-even
  return (u16)(u >> 16);
}
__device__ __forceinline__ float bf2f(u16 u) {
  return __builtin_bit_cast(float, (unsigned)u << 16);
}
__device__ __forceinline__ float sigm(float x) { return 1.f / (1.f + __expf(-x)); }

// ---------------- fused fp32 -> bf16 convert for all 4 tensors ----------------
__global__ __launch_bounds__(256) void k_cvt_all(
    const float* __restrict__ x, const float* __restrict__ Win,
    const float* __restrict__ Wdt, const float* __restrict__ Wout,
    u16* __restrict__ xbf, u16* __restrict__ winbf,
    u16* __restrict__ wdtbf, u16* __restrict__ woutbf)
{
  long i = (long)blockIdx.x * 256 + threadIdx.x;
  const float* src; u16* dst; long off;
  if (i < 1048576)            { src = x;    dst = xbf;    off = i; }
  else if (i < 1572864)       { src = Win;  dst = winbf;  off = i - 1048576; }
  else if (i < 1835008)       { src = Wdt;  dst = wdtbf;  off = i - 1572864; }
  else                        { src = Wout; dst = woutbf; off = i - 1835008; }
  float4 v = reinterpret_cast<const float4*>(src)[off];
  ushort4 o;
  o.x = f2bf(v.x); o.y = f2bf(v.y); o.z = f2bf(v.z); o.w = f2bf(v.w);
  reinterpret_cast<ushort4*>(dst)[off] = o;
}

// ---------------- bf16 MFMA GEMM: C[M][N] = A[M][K] * B[N][K]^T ----------------
// 32x32x16 frags, 2-buffer prefetch, BK=64, both-sides granule swizzle.
// NO setprio (m190 + R8-vs-R7 isolation: T5 regresses 2-phase GEMM here).
// Governing model (R1-R11): staging ingestion ~10.4 B/cyc/CU when >=2 blk/CU;
// latency wall below. G1 128x128@512 (2/CU), G2/G3 64x64@1024 (4/CU).
// EPI 0: fp32 store. EPI 1: bf16 x_proj / bf16 silu(res).
// EPI 3: bf16 softplus(delta) + fused scanA (2 chunks x 64 d per block).

__device__ __forceinline__ void gload16(const u16* g, u16* l) {
  __builtin_amdgcn_global_load_lds((const __attribute__((address_space(1))) void*)g,
                                   (__attribute__((address_space(3))) void*)l,
                                   16, 0, 0);
}

template<int EPI, int BM, int BN, int GX, int MINW>
__global__ __launch_bounds__(256, MINW) void k_gemm(
    const u16* __restrict__ A, const u16* __restrict__ B,
    float* __restrict__ outf, u16* __restrict__ outb, u16* __restrict__ outb2,
    const float* __restrict__ bias,
    const float* __restrict__ A_log, const float* __restrict__ Bp,
    float* __restrict__ hfin, float* __restrict__ sumdt,
    int M, int N, int K)
{
  constexpr int MI_ = BM / 64;     // 32x32 frags per wave in M (2x2 wave grid)
  constexpr int NI_ = BN / 64;
  __shared__ __align__(16) u16 sA[2 * BM * BK];
  __shared__ __align__(16) u16 sB[2 * BN * BK];
  const int t = threadIdx.x;
  const int wave = t >> 6, lane = t & 63;
  const int la = lane & 31, hi = lane >> 5;
  const int wr = wave >> 1, wc = wave & 1;

  // XCD-aware bijective swizzle (nwg % 8 == 0)
  const int nwg = gridDim.x;
  const int bid = blockIdx.x;
  const int wg  = (bid & 7) * (nwg >> 3) + (bid >> 3);
  const long bm = (long)(wg / GX) * BM;
  const long bn = (long)(wg % GX) * BN;

  f32x16 acc[MI_][NI_] = {};

  const int srow = t >> 3;                               // 0..31
  const int gslot8 = (((t & 7) ^ (srow & 7)) * 8);       // pre-swizzled source
  const u16* gA0 = A + (bm + srow) * (long)K + gslot8;
  const u16* gB0 = B + (bn + srow) * (long)K + gslot8;

  auto STAGE = [&](int buf, int k0) {
    #pragma unroll
    for (int i = 0; i < BM / 32; ++i)
      gload16(gA0 + (long)i * 32 * K + k0,
              &sA[buf * (BM * BK) + i * 2048 + wave * 512]);
    #pragma unroll
    for (int i = 0; i < BN / 32; ++i)
      gload16(gB0 + (long)i * 32 * K + k0,
              &sB[buf * (BN * BK) + i * 2048 + wave * 512]);
  };

  const int xr = la & 7;            // read-side XOR (granule units)
  STAGE(0, 0);
  __syncthreads();
  int cur = 0;
  for (int k0 = 0; k0 < K; k0 += BK) {
    if (k0 + BK < K) STAGE(cur ^ 1, k0 + BK);   // prefetch next tile
    const u16* pa = &sA[cur * (BM * BK)];
    const u16* pb = &sB[cur * (BN * BK)];
    bf16x8 af[4][MI_], bfr[4][NI_];
    #pragma unroll
    for (int ks = 0; ks < 4; ++ks) {
      const int co = ((ks * 2 + hi) ^ xr) * 8;  // granule slot -> u16 offset
      #pragma unroll
      for (int mi = 0; mi < MI_; ++mi)
        af[ks][mi] = *reinterpret_cast<const bf16x8*>(
            pa + (wr * (BM / 2) + mi * 32 + la) * BK + co);
      #pragma unroll
      for (int ni = 0; ni < NI_; ++ni)
        bfr[ks][ni] = *reinterpret_cast<const bf16x8*>(
            pb + (wc * (BN / 2) + ni * 32 + la) * BK + co);
    }
    #pragma unroll
    for (int ks = 0; ks < 4; ++ks)
      #pragma unroll
      for (int mi = 0; mi < MI_; ++mi)
        #pragma unroll
        for (int ni = 0; ni < NI_; ++ni)
          acc[mi][ni] = __builtin_amdgcn_mfma_f32_32x32x16_bf16(
              af[ks][mi], bfr[ks][ni], acc[mi][ni], 0, 0, 0);
    __syncthreads();   // drains vmcnt(0): next buf staged; cur reads complete
    cur ^= 1;
  }

  // ---------------- epilogue ----------------
  float* sDelta = (float*)sA;   // EPI3: 64x64 fp32 = 16 KB, LDS reuse post-loop

  #pragma unroll
  for (int mi = 0; mi < MI_; ++mi) {
    const long rowb = bm + wr * (BM / 2) + mi * 32 + 4 * hi;
    #pragma unroll
    for (int ni = 0; ni < NI_; ++ni) {
      const long col = bn + wc * (BN / 2) + ni * 32 + la;
      #pragma unroll
      for (int q = 0; q < 4; ++q)
        #pragma unroll
        for (int j = 0; j < 4; ++j) {
          const float v = acc[mi][ni][q * 4 + j];
          const long r = rowb + q * 8 + j;
          if (EPI == 0) {
            outf[r * N + col] = v;
          } else if (EPI == 1) {
            if (bn < DI) outb[r * DI + col] = f2bf(v);                    // x_proj
            else         outb2[r * DI + (col - DI)] = f2bf(v * sigm(v));  // silu(res)
          } else if (EPI == 3) {
            float z = v + bias[col];
            float sp = fmaxf(z, 0.f) + log1pf(__expf(-fabsf(z)));
            outb[r * N + col] = f2bf(sp);                 // delta bf16 for scanB
            sDelta[(int)(r - bm) * 64 + (int)(col - bn)] = sp;
          }
        }
    }
  }

  if (EPI == 3) {
    // fused scanA: 2 chunks x 64 d per block; thread = (chunk,d) x n-half
    __syncthreads();
    const int pair = t >> 1, half = t & 1;
    const int clocal = pair >> 6;          // 0..1
    const int dl = pair & 63;
    const int d = (int)bn + dl;
    const int b = (int)(bm >> 11);
    const int cglob = (int)((bm & 2047) >> 5) + clocal;
    const long grow0 = bm + clocal * 32;
    float Aa[8], Bb[8], h[8];
    #pragma unroll
    for (int n = 0; n < 8; ++n) {
      Aa[n] = -__expf(A_log[d * NSTATE + half * 8 + n]);
      Bb[n] = Bp[d * NSTATE + half * 8 + n];
      h[n] = 0.f;
    }
    float sdt = 0.f;
    for (int i = 0; i < CLEN; ++i) {
      float dt = sDelta[(clocal * 32 + i) * 64 + dl];
      float xv = bf2f(A[(grow0 + i) * (long)K + d]);     // A == xc_bf
      sdt += dt;
      float dx = dt * xv;
      #pragma unroll
      for (int n = 0; n < 8; ++n) {
        float da = __expf(dt * Aa[n]);
        h[n] = fmaf(da, h[n], dx * Bb[n]);
      }
    }
    const long hb = ((long)(b * NCHUNK + cglob) * NSTATE + half * 8) * DI + d;
    #pragma unroll
    for (int n = 0; n < 8; ++n) hfin[hb + (long)n * DI] = h[n];
    if (half == 0) sumdt[(long)(b * NCHUNK + cglob) * DI + d] = sdt;
  }
}

// ---------------- causal depthwise conv (K=4) + silu -> bf16, x8 vectorized ----
__global__ __launch_bounds__(256) void k_conv(
    const u16* __restrict__ xproj, const float* __restrict__ convw,
    const float* __restrict__ convb, u16* __restrict__ xcbf)
{
  const int idx = blockIdx.x * 256 + threadIdx.x;   // (m, d-octet)
  const int d0 = (idx & 127) * 8;
  const int m  = idx >> 7;
  const int l  = m & (SEQ - 1);
  float acc[8];
  #pragma unroll
  for (int di = 0; di < 8; ++di) acc[di] = convb[d0 + di];
  #pragma unroll
  for (int k = 0; k < 4; ++k) {
    if (l + k - 3 >= 0) {
      ushort4 v2 = *reinterpret_cast<const ushort4*>(&xproj[(long)(m + k - 3) * DI + d0]);
      ushort4 v3 = *reinterpret_cast<const ushort4*>(&xproj[(long)(m + k - 3) * DI + d0 + 4]);
      const u16 vv[8] = {v2.x, v2.y, v2.z, v2.w, v3.x, v3.y, v3.z, v3.w};
      #pragma unroll
      for (int di = 0; di < 8; ++di)
        acc[di] = fmaf(convw[(d0 + di) * 4 + k], bf2f(vv[di]), acc[di]);
    }
  }
  u16 ov[8];
  #pragma unroll
  for (int di = 0; di < 8; ++di) {
    float s = acc[di] * sigm(acc[di]);
    ov[di] = f2bf(s);
  }
  ushort4 o0 = {ov[0], ov[1], ov[2], ov[3]}, o1 = {ov[4], ov[5], ov[6], ov[7]};
  *reinterpret_cast<ushort4*>(&xcbf[(long)m * DI + d0]) = o0;
  *reinterpret_cast<ushort4*>(&xcbf[(long)m * DI + d0 + 4]) = o1;
}

// ---------------- scan combine + pass B ----------------
__global__ __launch_bounds__(256) void k_combine(
    const float* __restrict__ hfin, const float* __restrict__ sumdt_buf,
    const float* __restrict__ A_log, float* __restrict__ hstart)
{
  const int idx = blockIdx.x * 256 + threadIdx.x;   // 32768 threads
  const int d = idx & (DI - 1);
  const int n = (idx >> 10) & (NSTATE - 1);
  const int b = idx >> 14;
  const float Aa = -__expf(A_log[d * NSTATE + n]);
  float h = 0.f;
  for (int c = 0; c < NCHUNK; ++c) {
    const long sb = ((long)(b * NCHUNK + c) * NSTATE + n) * DI + d;
    hstart[sb] = h;
    float sdt = sumdt_buf[(long)(b * NCHUNK + c) * DI + d];
    h = fmaf(__expf(Aa * sdt), h, hfin[sb]);
  }
}

__global__ __launch_bounds__(256) void k_scanB(
    const u16* __restrict__ delta, const u16* __restrict__ xc,
    const float* __restrict__ A_log, const float* __restrict__ Bp,
    const float* __restrict__ Cp, const float* __restrict__ Dp,
    const u16* __restrict__ sres, const float* __restrict__ hstart,
    u16* __restrict__ gated)
{
  const int tid = threadIdx.x, blk = blockIdx.x;    // 512 blocks
  const int d = (blk & 3) * 256 + tid;
  const int c = (blk >> 2) & (NCHUNK - 1);
  const int b = blk >> 8;
  float Aa[NSTATE], Bb[NSTATE], Cc[NSTATE], h[NSTATE];
  #pragma unroll
  for (int n = 0; n < NSTATE; ++n) {
    Aa[n] = -__expf(A_log[d * NSTATE + n]);
    Bb[n] = Bp[d * NSTATE + n];
    Cc[n] = Cp[d * NSTATE + n];
  }
  const float Dd = Dp[d];
  const long sb = ((long)(b * NCHUNK + c) * NSTATE) * DI + d;
  #pragma unroll
  for (int n = 0; n < NSTATE; ++n) h[n] = hstart[sb + (long)n * DI];
  const long base = ((long)(b * SEQ + c * CLEN)) * DI + d;
  for (int i = 0; i < CLEN; ++i) {
    float dt = bf2f(delta[base + (long)i * DI]);
    float x  = bf2f(xc[base + (long)i * DI]);
    float dx = dt * x;
    float y = 0.f;
    #pragma unroll
    for (int n = 0; n < NSTATE; ++n) {
      float da = __expf(dt * Aa[n]);
      h[n] = fmaf(da, h[n], dx * Bb[n]);
      y = fmaf(h[n], Cc[n], y);
    }
    float xs = fmaf(x, Dd, y);
    float g = xs * bf2f(sres[base + (long)i * DI]);
    gated[base + (long)i * DI] = f2bf(g);
  }
}

// ---------------- host launch ----------------
extern "C" void kernel_launch(void* const* d_in, const int* in_sizes, int n_in,
                              void* d_out, int out_size, void* d_ws, size_t ws_size,
                              hipStream_t stream)
{
  const float* x      = (const float*)d_in[0];
  const float* W_in   = (const float*)d_in[1];
  const float* conv_w = (const float*)d_in[2];
  const float* conv_b = (const float*)d_in[3];
  const float* W_dt   = (const float*)d_in[4];
  const float* b_dt   = (const float*)d_in[5];
  const float* A_log  = (const float*)d_in[6];
  const float* Bp     = (const float*)d_in[7];
  const float* Cp     = (const float*)d_in[8];
  const float* Dp     = (const float*)d_in[9];
  const float* W_out  = (const float*)d_in[10];
  float* out = (float*)d_out;

  const long MD = (long)NROW * DI;          // 4194304

  char* ws = (char*)d_ws;
  u16*   xproj_bf = (u16*)ws;               ws += MD * 2;   // x_proj bf16
  u16*   silu_bf  = (u16*)ws;               ws += MD * 2;   // silu(res) bf16
  u16*   delta_bf = (u16*)ws;               ws += MD * 2;   // softplus out bf16
  u16*   xc_bf    = (u16*)ws;               ws += MD * 2;   // conv+silu bf16
  u16*   xbf      = (u16*)ws;               ws += MD * 2;   // x bf16; later gated
  u16*   Win_bf   = (u16*)ws;               ws += (long)2 * DI * DM * 2;
  u16*   Wdt_bf   = (u16*)ws;               ws += (long)DI * DI * 2;
  u16*   Wout_bf  = (u16*)ws;               ws += (long)DM * DI * 2;
  float* hfin     = (float*)ws;             ws += (long)BATCH * NCHUNK * NSTATE * DI * 4;
  float* sumdt    = (float*)ws;             ws += (long)BATCH * NCHUNK * DI * 4;
  float* hstart   = (float*)ws;             ws += (long)BATCH * NCHUNK * NSTATE * DI * 4;

  u16* gated = xbf;      // alias: x_bf16 dead before gated is written

  // 1) fused fp32 -> bf16 conversion (x, W_in, W_dt, W_out)
  k_cvt_all<<<dim3(8192), dim3(256), 0, stream>>>(
      x, W_in, W_dt, W_out, xbf, Win_bf, Wdt_bf, Wout_bf);

  // 2) GEMM1: xr = x @ W_in^T -> x_proj (bf16), silu_res (bf16)
  //    128x128 tile, grid 512 (2/CU)
  k_gemm<1, 128, 128, 16, 2><<<dim3(512), dim3(256), 0, stream>>>(
      xbf, Win_bf, nullptr, xproj_bf, silu_bf, nullptr,
      nullptr, nullptr, nullptr, nullptr, NROW, 2 * DI, DM);

  // 3) causal depthwise conv + silu -> bf16 (x8 vectorized)
  k_conv<<<dim3((unsigned)(MD / 8 / 256)), dim3(256), 0, stream>>>(
      xproj_bf, conv_w, conv_b, xc_bf);

  // 4) GEMM2 + fused scanA: delta = softplus(xc @ W_dt^T + b_dt); local scan
  //    64x64 tile, grid 1024 (4/CU)
  k_gemm<3, 64, 64, 16, 2><<<dim3(1024), dim3(256), 0, stream>>>(
      xc_bf, Wdt_bf, nullptr, delta_bf, nullptr, b_dt,
      A_log, Bp, hfin, sumdt, NROW, DI, DI);

  // 5) combine + scanB
  k_combine<<<dim3(BATCH * NSTATE * DI / 256), dim3(256), 0, stream>>>(
      hfin, sumdt, A_log, hstart);
  k_scanB<<<dim3(BATCH * NCHUNK * (DI / 256)), dim3(256), 0, stream>>>(
      delta_bf, xc_bf, A_log, Bp, Cp, Dp, silu_bf, hstart, gated);

  // 6) GEMM3: out = gated @ W_out^T (fp32 out)
  //    64x64 tile, grid 1024 (4/CU)
  k_gemm<0, 64, 64, 16, 4><<<dim3(1024), dim3(256), 0, stream>>>(
      gated, Wout_bf, out, nullptr, nullptr, nullptr,
      nullptr, nullptr, nullptr, nullptr, NROW, DM, DI);
}